// Round 1
// baseline (1216.560 us; speedup 1.0000x reference)
//
#include <hip/hip_runtime.h>
#include <stdint.h>
#include <stddef.h>

// Problem: SEQ=8192, IN_DIM=OUT_DIM=1024, single-head causal attention with QKV proj.
// Pipeline: cast fp32->bf16 -> fused QKV MFMA GEMM -> V transpose -> flash attention.

#define SEQ   8192
#define DIM   1024

typedef __bf16 bf16x8 __attribute__((ext_vector_type(8)));
typedef float  f32x4  __attribute__((ext_vector_type(4)));
typedef uint16_t u16x8 __attribute__((ext_vector_type(8)));

#define MFMA16(a, b, c) __builtin_amdgcn_mfma_f32_16x16x32_bf16((a), (b), (c), 0, 0, 0)

__device__ __forceinline__ uint16_t f2bf(float f) {
  uint32_t u = __builtin_bit_cast(uint32_t, f);
  return (uint16_t)((u + 0x7fffu + ((u >> 16) & 1u)) >> 16);
}

// ---------------------------------------------------------------- cast kernel
__global__ __launch_bounds__(256) void cast_f32_bf16(const float* __restrict__ src,
                                                     uint16_t* __restrict__ dst, int n) {
  int i = (blockIdx.x * 256 + threadIdx.x) * 4;
  if (i + 3 < n) {
    float4 v = *(const float4*)(src + i);
    ushort4 o;
    o.x = f2bf(v.x); o.y = f2bf(v.y); o.z = f2bf(v.z); o.w = f2bf(v.w);
    *(ushort4*)(dst + i) = o;
  }
}

// ------------------------------------------------------------- QKV GEMM
// C[m,n] = sum_k A[m,k] * B[n,k]   (A=[8192,1024] bf16, B=wcat [3072,1024] bf16)
// 128x128 tile, BK=64, 4 waves each computing a 64x64 quadrant (4x4 mfma tiles).
// n in [0,1024) -> Q, [1024,2048) -> K, [2048,3072) -> V (all row-major [8192,1024]).
__global__ __launch_bounds__(256) void qkv_gemm(const uint16_t* __restrict__ A,
                                                const uint16_t* __restrict__ B,
                                                uint16_t* __restrict__ Qb,
                                                uint16_t* __restrict__ Kb,
                                                uint16_t* __restrict__ Vb) {
  // +8 pad: row stride 144B = 36 dwords = 4 mod 32 banks -> 2-way aliasing (free)
  __shared__ __align__(16) uint16_t As[128][72];
  __shared__ __align__(16) uint16_t Bs[128][72];
  const int t    = threadIdx.x;
  const int w    = t >> 6;
  const int lane = t & 63;
  const int lm   = lane & 15;
  const int qd   = lane >> 4;
  const int wrow = (w >> 1) * 64;
  const int wcol = (w & 1) * 64;
  const int rowbase = blockIdx.y * 128;
  const int colbase = blockIdx.x * 128;

  f32x4 acc[4][4] = {};

  for (int kb = 0; kb < DIM; kb += 64) {
    __syncthreads();
#pragma unroll
    for (int rep = 0; rep < 4; ++rep) {
      int i = rep * 256 + t;
      int r = i >> 3, c8 = i & 7;
      *(uint4*)(&As[r][c8 * 8]) =
          *(const uint4*)(A + (size_t)(rowbase + r) * DIM + kb + c8 * 8);
    }
#pragma unroll
    for (int rep = 0; rep < 4; ++rep) {
      int i = rep * 256 + t;
      int r = i >> 3, c8 = i & 7;
      *(uint4*)(&Bs[r][c8 * 8]) =
          *(const uint4*)(B + (size_t)(colbase + r) * DIM + kb + c8 * 8);
    }
    __syncthreads();
#pragma unroll
    for (int kc = 0; kc < 2; ++kc) {
      bf16x8 af[4], bfr[4];
#pragma unroll
      for (int mt = 0; mt < 4; ++mt)
        af[mt] = *(const bf16x8*)(&As[wrow + mt * 16 + lm][kc * 32 + qd * 8]);
#pragma unroll
      for (int nt = 0; nt < 4; ++nt)
        bfr[nt] = *(const bf16x8*)(&Bs[wcol + nt * 16 + lm][kc * 32 + qd * 8]);
#pragma unroll
      for (int mt = 0; mt < 4; ++mt)
#pragma unroll
        for (int nt = 0; nt < 4; ++nt)
          acc[mt][nt] = MFMA16(af[mt], bfr[nt], acc[mt][nt]);
    }
  }

#pragma unroll
  for (int mt = 0; mt < 4; ++mt)
#pragma unroll
    for (int nt = 0; nt < 4; ++nt)
#pragma unroll
      for (int r = 0; r < 4; ++r) {
        int m = rowbase + wrow + mt * 16 + qd * 4 + r;
        int n = colbase + wcol + nt * 16 + lm;
        uint16_t v = f2bf(acc[mt][nt][r]);
        if (n < 1024)       Qb[(size_t)m * DIM + n]          = v;
        else if (n < 2048)  Kb[(size_t)m * DIM + (n - 1024)] = v;
        else                Vb[(size_t)m * DIM + (n - 2048)] = v;
      }
}

// ------------------------------------------------------------ V transpose
// Vb [8192,1024] -> Vt [1024,8192] via 64x64 LDS tiles.
__global__ __launch_bounds__(256) void transpose_v(const uint16_t* __restrict__ Vb,
                                                   uint16_t* __restrict__ Vt) {
  __shared__ __align__(16) uint16_t tile[64][72];
  const int t  = threadIdx.x;
  const int mb = blockIdx.x * 64;
  const int db = blockIdx.y * 64;
#pragma unroll
  for (int rep = 0; rep < 2; ++rep) {
    int i = rep * 256 + t;
    int r = i >> 3, c = (i & 7) * 8;
    *(uint4*)(&tile[r][c]) = *(const uint4*)(Vb + (size_t)(mb + r) * DIM + db + c);
  }
  __syncthreads();
#pragma unroll
  for (int rep = 0; rep < 2; ++rep) {
    int i = rep * 256 + t;
    int d = i >> 3, mq = (i & 7) * 8;
    u16x8 v;
#pragma unroll
    for (int u = 0; u < 8; ++u) v[u] = tile[mq + u][d];
    *(u16x8*)(Vt + (size_t)(db + d) * SEQ + mb + mq) = v;
  }
}

// ------------------------------------------------------------ flash attention
// Br=32 rows/block, Bc=128 keys/iter, 4 waves (256 thr), grid = SEQ/32 = 256.
// Wave w: S-phase owns S cols [32w,32w+32); PV-phase owns output d in [256w,256w+256).
__global__ __launch_bounds__(256) void attn_kernel(const uint16_t* __restrict__ Qb,
                                                   const uint16_t* __restrict__ Kb,
                                                   const uint16_t* __restrict__ Vt,
                                                   float* __restrict__ out) {
  __shared__ __align__(16) uint16_t Qs[32][1032];  // +8 pad -> 2-way banks (free)
  __shared__ float S[32][129];                     // +1 pad
  __shared__ __align__(16) uint16_t P[32][136];    // +8 pad
  __shared__ float alpha_s[32];
  __shared__ float l_s[32];

  const int t    = threadIdx.x;
  const int w    = t >> 6;
  const int lane = t & 63;
  const int lm   = lane & 15;
  const int qd   = lane >> 4;
  const int q    = blockIdx.x;
  const int row0 = q * 32;

  // stage Q tile (32 x 1024 bf16)
#pragma unroll
  for (int rep = 0; rep < 16; ++rep) {
    int i = rep * 256 + t;
    int r = i >> 7, c = (i & 127) * 8;
    *(uint4*)(&Qs[r][c]) = *(const uint4*)(Qb + (size_t)(row0 + r) * DIM + c);
  }
  __syncthreads();

  f32x4 o_acc[2][16] = {};

  const int   srow  = t >> 3;
  const int   scol0 = (t & 7) * 16;
  float m_run = -1e30f, l_run = 0.0f;
  const float c1 = 0.045084220027780106f;  // log2(e) / sqrt(1024)

  const int jn = q / 4 + 1;  // # of 128-key tiles; only the last needs masking
  for (int j = 0; j < jn; ++j) {
    // ---- Phase A: S[32,128] = Q * K^T (raw dots; scale folded into exponent)
    f32x4 sacc[2][2] = {};
    const uint16_t* kp0 = Kb + (size_t)(j * 128 + w * 32 + lm) * DIM + qd * 8;
    const uint16_t* kp1 = kp0 + (size_t)16 * DIM;
    const uint16_t* ap  = &Qs[lm][qd * 8];
#pragma unroll
    for (int kc = 0; kc < 32; ++kc) {
      bf16x8 a0 = *(const bf16x8*)(ap + kc * 32);
      bf16x8 a1 = *(const bf16x8*)(ap + 16 * 1032 + kc * 32);
      bf16x8 b0 = *(const bf16x8*)(kp0 + kc * 32);
      bf16x8 b1 = *(const bf16x8*)(kp1 + kc * 32);
      sacc[0][0] = MFMA16(a0, b0, sacc[0][0]);
      sacc[1][0] = MFMA16(a1, b0, sacc[1][0]);
      sacc[0][1] = MFMA16(a0, b1, sacc[0][1]);
      sacc[1][1] = MFMA16(a1, b1, sacc[1][1]);
    }
#pragma unroll
    for (int mt = 0; mt < 2; ++mt)
#pragma unroll
      for (int nt = 0; nt < 2; ++nt)
#pragma unroll
        for (int r = 0; r < 4; ++r)
          S[mt * 16 + qd * 4 + r][w * 32 + nt * 16 + lm] = sacc[mt][nt][r];
    __syncthreads();

    // ---- Phase B: online softmax (8 threads per row, shfl width-8 reductions)
    const bool maskt = (j == jn - 1);
    float sv[16];
    float mx = -1e30f;
#pragma unroll
    for (int c = 0; c < 16; ++c) {
      float s = S[srow][scol0 + c];
      if (maskt && (j * 128 + scol0 + c > row0 + srow)) s = -1e30f;
      sv[c] = s;
      mx = fmaxf(mx, s);
    }
    mx = fmaxf(mx, __shfl_xor(mx, 1, 8));
    mx = fmaxf(mx, __shfl_xor(mx, 2, 8));
    mx = fmaxf(mx, __shfl_xor(mx, 4, 8));
    float mn    = fmaxf(m_run, mx);
    float alpha = exp2f((m_run - mn) * c1);
    float psum  = 0.0f;
#pragma unroll
    for (int c = 0; c < 16; ++c) {
      float p = exp2f((sv[c] - mn) * c1);
      psum += p;
      P[srow][scol0 + c] = f2bf(p);
    }
    psum += __shfl_xor(psum, 1, 8);
    psum += __shfl_xor(psum, 2, 8);
    psum += __shfl_xor(psum, 4, 8);
    l_run = alpha * l_run + psum;
    m_run = mn;
    if ((t & 7) == 0) alpha_s[srow] = alpha;
    __syncthreads();

    // ---- Phase C: O = alpha*O + P @ V  (wave w owns d-slice [256w, 256w+256))
    float al[2][4];
#pragma unroll
    for (int mt = 0; mt < 2; ++mt)
#pragma unroll
      for (int r = 0; r < 4; ++r)
        al[mt][r] = alpha_s[mt * 16 + qd * 4 + r];
#pragma unroll
    for (int mt = 0; mt < 2; ++mt)
#pragma unroll
      for (int nt = 0; nt < 16; ++nt)
#pragma unroll
        for (int r = 0; r < 4; ++r)
          o_acc[mt][nt][r] *= al[mt][r];

    const uint16_t* vtb = Vt + (size_t)(w * 256 + lm) * SEQ + j * 128 + qd * 8;
#pragma unroll
    for (int kc2 = 0; kc2 < 4; ++kc2) {
      bf16x8 a0 = *(const bf16x8*)(&P[lm][kc2 * 32 + qd * 8]);
      bf16x8 a1 = *(const bf16x8*)(&P[16 + lm][kc2 * 32 + qd * 8]);
#pragma unroll
      for (int nt = 0; nt < 16; ++nt) {
        bf16x8 b = *(const bf16x8*)(vtb + (size_t)nt * 16 * SEQ + kc2 * 32);
        o_acc[0][nt] = MFMA16(a0, b, o_acc[0][nt]);
        o_acc[1][nt] = MFMA16(a1, b, o_acc[1][nt]);
      }
    }
    // no barrier needed here: next S/P/alpha writes are ordered by the two
    // in-loop barriers (S written in next A only after this C per-thread;
    // P/alpha written in next B which is after next A's barrier).
  }

  // ---- epilogue: O /= l
  if ((t & 7) == 0) l_s[srow] = l_run;
  __syncthreads();
  float li[2][4];
#pragma unroll
  for (int mt = 0; mt < 2; ++mt)
#pragma unroll
    for (int r = 0; r < 4; ++r)
      li[mt][r] = 1.0f / l_s[mt * 16 + qd * 4 + r];
#pragma unroll
  for (int mt = 0; mt < 2; ++mt)
#pragma unroll
    for (int nt = 0; nt < 16; ++nt)
#pragma unroll
      for (int r = 0; r < 4; ++r)
        out[(size_t)(row0 + mt * 16 + qd * 4 + r) * DIM + w * 256 + nt * 16 + lm] =
            o_acc[mt][nt][r] * li[mt][r];
}

// ---------------------------------------------------------------- launch
extern "C" void kernel_launch(void* const* d_in, const int* in_sizes, int n_in,
                              void* d_out, int out_size, void* d_ws, size_t ws_size,
                              hipStream_t stream) {
  (void)in_sizes; (void)n_in; (void)out_size; (void)ws_size;
  const float* x  = (const float*)d_in[0];
  const float* wq = (const float*)d_in[1];
  const float* wk = (const float*)d_in[2];
  const float* wv = (const float*)d_in[3];
  float* out = (float*)d_out;

  char* ws = (char*)d_ws;
  uint16_t* xb   = (uint16_t*)(ws);                         // 16 MB
  uint16_t* wcat = (uint16_t*)(ws + 16777216);              // 6 MB  [3072,1024]
  uint16_t* Qb   = (uint16_t*)(ws + 23068672);              // 16 MB [8192,1024]
  uint16_t* Kb   = (uint16_t*)(ws + 39845888);              // 16 MB [8192,1024]
  uint16_t* Vb   = (uint16_t*)(ws + 56623104);              // 16 MB [8192,1024]
  uint16_t* Vt   = (uint16_t*)(ws + 73400320);              // 16 MB [1024,8192]

  cast_f32_bf16<<<8192, 256, 0, stream>>>(x,  xb,               SEQ * DIM);
  cast_f32_bf16<<<1024, 256, 0, stream>>>(wq, wcat,             DIM * DIM);
  cast_f32_bf16<<<1024, 256, 0, stream>>>(wk, wcat + DIM * DIM, DIM * DIM);
  cast_f32_bf16<<<1024, 256, 0, stream>>>(wv, wcat + 2 * DIM * DIM, DIM * DIM);

  qkv_gemm<<<dim3(24, 64), 256, 0, stream>>>(xb, wcat, Qb, Kb, Vb);
  transpose_v<<<dim3(SEQ / 64, DIM / 64), 256, 0, stream>>>(Vb, Vt);
  attn_kernel<<<SEQ / 32, 256, 0, stream>>>(Qb, Kb, Vt, out);
}